// Round 10
// baseline (112.379 us; speedup 1.0000x reference)
//
#include <hip/hip_runtime.h>

#define D 64
#define ROWS 64
#define TPB 256

typedef float f4 __attribute__((ext_vector_type(4)));
typedef short s8 __attribute__((ext_vector_type(8)));

static __device__ __forceinline__ unsigned short f2bf(float x) {
  union { float f; unsigned u; } v; v.f = x;
  return (unsigned short)((v.u + 0x7FFFu + ((v.u >> 16) & 1u)) >> 16);
}

static __device__ __forceinline__ s8 pack8(f4 a, f4 b) {
  s8 r;
  r[0] = (short)f2bf(a.x); r[1] = (short)f2bf(a.y);
  r[2] = (short)f2bf(a.z); r[3] = (short)f2bf(a.w);
  r[4] = (short)f2bf(b.x); r[5] = (short)f2bf(b.y);
  r[6] = (short)f2bf(b.z); r[7] = (short)f2bf(b.w);
  return r;
}

static __device__ __forceinline__ f4 fma4s(float a, f4 b, f4 c) {
  f4 r;
  r.x = fmaf(a, b.x, c.x);
  r.y = fmaf(a, b.y, c.y);
  r.z = fmaf(a, b.z, c.z);
  r.w = fmaf(a, b.w, c.w);
  return r;
}

static __device__ __forceinline__ f4 prelu4(f4 p, float a) {
  f4 r;
  r.x = p.x >= 0.0f ? p.x : a * p.x;
  r.y = p.y >= 0.0f ? p.y : a * p.y;
  r.z = p.z >= 0.0f ? p.z : a * p.z;
  r.w = p.w >= 0.0f ? p.w : a * p.w;
  return r;
}

static __device__ __forceinline__ float dot4(f4 x, f4 y, f4 z, float acc) {
  // acc += <x+y, z>
  acc = fmaf(x.x + y.x, z.x, acc);
  acc = fmaf(x.y + y.y, z.y, acc);
  acc = fmaf(x.z + y.z, z.z, acc);
  acc = fmaf(x.w + y.w, z.w, acc);
  return acc;
}

// R10: drop the h/keys LDS round-trip (R9 was latency-bound at 31% occupancy,
// 49.7KB LDS, 3 barriers, nothing saturated). Lanes load their MFMA
// B-fragments DIRECTLY from global f32 (row j0+wv*16+rl, bytes
// [32g+128ks,+32) contiguous per lane) and cvt to bf16 in regs. Gate dot is
// computed from the same f32 values pre-pack (+shfl_xor 16/32: lanes of equal
// rl cover disjoint k). Residual h is re-read from global in D-frag layout
// (L2-hot). Only U/V (bf16, XOR-swizzled) + cc remain in LDS (16.5KB ->
// up to 9 blocks/CU by LDS); ONE barrier total.
// MFMA mapping as R9 (verified): A[m][k]=U[cb*16+m][k] via lane rl=m,
// slot asl=ks*4+g; B[k][n]=hb[n][k] via lane n=rl, k=8g+j+32ks;
// D: lane(g,rl) holds D[m=16cb+4g+reg][n=rl].
__global__ __launch_bounds__(TPB, 4) void dmc_fused(
    const float* __restrict__ h,
    const float* __restrict__ keys,
    const float* __restrict__ s,
    const float* __restrict__ U,
    const float* __restrict__ V,
    const float* __restrict__ W,
    const float* __restrict__ bias,
    const float* __restrict__ prelu_a,
    float* __restrict__ out,
    const int nblocks) {
  __shared__ __align__(16) unsigned short Ub[D * D];  // 8KB bf16, swizzled
  __shared__ __align__(16) unsigned short Vb[D * D];  // 8KB
  __shared__ __align__(16) float cc[D];

  const int tid  = threadIdx.x;
  const int lane = tid & 63;
  const int wv   = tid >> 6;            // 0..3 = batch row-block
  const int j0   = blockIdx.x * ROWS;
  const int nrem = nblocks - j0;

  // ---- stage U, V -> bf16 LDS [c][64k], 16B chunk sl at phys = sl^(c&7) ----
  const f4* __restrict__ Ug = reinterpret_cast<const f4*>(U);
  const f4* __restrict__ Vg = reinterpret_cast<const f4*>(V);
  s8* __restrict__ Ub8w = reinterpret_cast<s8*>(Ub);
  s8* __restrict__ Vb8w = reinterpret_cast<s8*>(Vb);
  #pragma unroll
  for (int t = 0; t < 2; ++t) {
    const int m  = tid + TPB * t;       // 0..511 chunk id
    const int c  = m >> 3;
    const int sl = m & 7;
    Ub8w[c * 8 + (sl ^ (c & 7))] = pack8(Ug[c * 16 + sl * 2], Ug[c * 16 + sl * 2 + 1]);
    Vb8w[c * 8 + (sl ^ (c & 7))] = pack8(Vg[c * 16 + sl * 2], Vg[c * 16 + sl * 2 + 1]);
  }

  // ---- cc[c] = bias[c] + W[c,:] @ s ----
  if (tid < D) {
    const f4* __restrict__ wr = reinterpret_cast<const f4*>(W + tid * D);
    const f4* __restrict__ sr = reinterpret_cast<const f4*>(s);
    float acc = bias[tid];
    #pragma unroll
    for (int q = 0; q < 16; ++q) {
      const f4 wq = wr[q];
      const f4 sq = sr[q];
      acc = fmaf(wq.x, sq.x, acc);
      acc = fmaf(wq.y, sq.y, acc);
      acc = fmaf(wq.z, sq.z, acc);
      acc = fmaf(wq.w, sq.w, acc);
    }
    cc[tid] = acc;
  }
  __syncthreads();

  // ---- per-lane geometry ----
  const int g  = lane >> 4;             // 0..3
  const int rl = lane & 15;             // MFMA n (batch row) / m (U row)
  const int r  = wv * 16 + rl;          // batch row within tile
  const int rc = (r < nrem) ? r : (nrem - 1);  // clamped for safe loads

  const f4* __restrict__ hrow = reinterpret_cast<const f4*>(h + (size_t)(j0 + rc) * D);
  const f4* __restrict__ krow = reinterpret_cast<const f4*>(keys + (size_t)(j0 + rc) * D);
  const f4* __restrict__ sg4  = reinterpret_cast<const f4*>(s);

  // ---- B-fragments from global + gate partial dot (f32, pre-pack) ----
  const f4 h0a = hrow[2 * g];      const f4 h0b = hrow[2 * g + 1];
  const f4 h1a = hrow[8 + 2 * g];  const f4 h1b = hrow[8 + 2 * g + 1];
  const f4 k0a = krow[2 * g];      const f4 k0b = krow[2 * g + 1];
  const f4 k1a = krow[8 + 2 * g];  const f4 k1b = krow[8 + 2 * g + 1];

  float gd = 0.0f;
  gd = dot4(h0a, k0a, sg4[2 * g], gd);
  gd = dot4(h0b, k0b, sg4[2 * g + 1], gd);
  gd = dot4(h1a, k1a, sg4[8 + 2 * g], gd);
  gd = dot4(h1b, k1b, sg4[8 + 2 * g + 1], gd);

  const s8 bh0 = pack8(h0a, h0b);
  const s8 bh1 = pack8(h1a, h1b);
  const s8 bk0 = pack8(k0a, k0b);
  const s8 bk1 = pack8(k1a, k1b);

  // ---- accumulators from cc ----
  const f4* __restrict__ cc4 = reinterpret_cast<const f4*>(cc);
  f4 acc0 = cc4[0 + g];
  f4 acc1 = cc4[4 + g];
  f4 acc2 = cc4[8 + g];
  f4 acc3 = cc4[12 + g];

  // ---- MFMA main: K=64 as 2 slices of 32 ----
  const s8* __restrict__ Ub8 = reinterpret_cast<const s8*>(Ub);
  const s8* __restrict__ Vb8 = reinterpret_cast<const s8*>(Vb);
  #pragma unroll
  for (int ks = 0; ks < 2; ++ks) {
    const int asl = ks * 4 + g;
    const s8 bh = (ks == 0) ? bh0 : bh1;
    const s8 bk = (ks == 0) ? bk0 : bk1;
    const int c0i = 0 * 16 + rl, c1i = 1 * 16 + rl;
    const int c2i = 2 * 16 + rl, c3i = 3 * 16 + rl;
    const s8 au0 = Ub8[c0i * 8 + (asl ^ (c0i & 7))];
    const s8 au1 = Ub8[c1i * 8 + (asl ^ (c1i & 7))];
    const s8 au2 = Ub8[c2i * 8 + (asl ^ (c2i & 7))];
    const s8 au3 = Ub8[c3i * 8 + (asl ^ (c3i & 7))];
    const s8 av0 = Vb8[c0i * 8 + (asl ^ (c0i & 7))];
    const s8 av1 = Vb8[c1i * 8 + (asl ^ (c1i & 7))];
    const s8 av2 = Vb8[c2i * 8 + (asl ^ (c2i & 7))];
    const s8 av3 = Vb8[c3i * 8 + (asl ^ (c3i & 7))];
    acc0 = __builtin_amdgcn_mfma_f32_16x16x32_bf16(au0, bh, acc0, 0, 0, 0);
    acc1 = __builtin_amdgcn_mfma_f32_16x16x32_bf16(au1, bh, acc1, 0, 0, 0);
    acc2 = __builtin_amdgcn_mfma_f32_16x16x32_bf16(au2, bh, acc2, 0, 0, 0);
    acc3 = __builtin_amdgcn_mfma_f32_16x16x32_bf16(au3, bh, acc3, 0, 0, 0);
    acc0 = __builtin_amdgcn_mfma_f32_16x16x32_bf16(av0, bk, acc0, 0, 0, 0);
    acc1 = __builtin_amdgcn_mfma_f32_16x16x32_bf16(av1, bk, acc1, 0, 0, 0);
    acc2 = __builtin_amdgcn_mfma_f32_16x16x32_bf16(av2, bk, acc2, 0, 0, 0);
    acc3 = __builtin_amdgcn_mfma_f32_16x16x32_bf16(av3, bk, acc3, 0, 0, 0);
  }

  // ---- gate reduce (lanes of equal rl hold disjoint k-ranges) ----
  gd += __shfl_xor(gd, 16);
  gd += __shfl_xor(gd, 32);
  const float gt = 1.0f / (1.0f + __expf(-gd));
  const float a  = prelu_a[0];

  // ---- gated residual: h re-read from global (L2-hot) in D-frag layout ----
  const f4 hr0 = hrow[0 + g];
  const f4 hr1 = hrow[4 + g];
  const f4 hr2 = hrow[8 + g];
  const f4 hr3 = hrow[12 + g];
  f4 o0 = fma4s(gt, prelu4(acc0, a), hr0);
  f4 o1 = fma4s(gt, prelu4(acc1, a), hr1);
  f4 o2 = fma4s(gt, prelu4(acc2, a), hr2);
  f4 o3 = fma4s(gt, prelu4(acc3, a), hr3);

  float ss = o0.x * o0.x + o0.y * o0.y + o0.z * o0.z + o0.w * o0.w;
  ss = fmaf(o1.x, o1.x, ss); ss = fmaf(o1.y, o1.y, ss);
  ss = fmaf(o1.z, o1.z, ss); ss = fmaf(o1.w, o1.w, ss);
  ss = fmaf(o2.x, o2.x, ss); ss = fmaf(o2.y, o2.y, ss);
  ss = fmaf(o2.z, o2.z, ss); ss = fmaf(o2.w, o2.w, ss);
  ss = fmaf(o3.x, o3.x, ss); ss = fmaf(o3.y, o3.y, ss);
  ss = fmaf(o3.z, o3.z, ss); ss = fmaf(o3.w, o3.w, ss);
  ss += __shfl_xor(ss, 16);
  ss += __shfl_xor(ss, 32);
  const float rn = rsqrtf(ss);

  if (r < nrem) {
    float* __restrict__ orow = out + (size_t)(j0 + r) * D + g * 4;
    *reinterpret_cast<f4*>(orow +  0) = o0 * rn;
    *reinterpret_cast<f4*>(orow + 16) = o1 * rn;
    *reinterpret_cast<f4*>(orow + 32) = o2 * rn;
    *reinterpret_cast<f4*>(orow + 48) = o3 * rn;
  }
}

extern "C" void kernel_launch(void* const* d_in, const int* in_sizes, int n_in,
                              void* d_out, int out_size, void* d_ws, size_t ws_size,
                              hipStream_t stream) {
  const float* s       = (const float*)d_in[0];
  const float* h       = (const float*)d_in[1];
  const float* keys    = (const float*)d_in[2];
  const float* U       = (const float*)d_in[3];
  const float* V       = (const float*)d_in[4];
  const float* W       = (const float*)d_in[5];
  const float* bias    = (const float*)d_in[6];
  const float* prelu_a = (const float*)d_in[7];
  float* out = (float*)d_out;

  const int nblocks = in_sizes[1] / D;
  const int grid = (nblocks + ROWS - 1) / ROWS;
  dmc_fused<<<grid, TPB, 0, stream>>>(h, keys, s, U, V, W, bias, prelu_a, out,
                                      nblocks);
}